// Round 14
// baseline (73.671 us; speedup 1.0000x reference)
//
#include <hip/hip_runtime.h>
#include <math.h>
#include <stdint.h>

#define KK 5
#define PADK 2
#define C_IN 8
#define O_OUT 8
#define HH 512
#define WW 512
#define TH 8
#define TW 128
#define CH 4                      // channels per staged half
#define LROWS 12                  // TH + 4
#define LCOLS 136                 // TW + 4 halo, padded (f32 cols)
#define WCHUNK 64                 // dwords per (og,c) chunk (50 used), 256B aligned
#define NW (O_OUT * C_IN * KK * KK)   // 1600
#define XHALF (CH * LROWS * (LCOLS / 2))   // float2 slots per half = 3264

// Full-rate VOP3 3-input max.
static __device__ __forceinline__ float max3f(float a, float b, float c) {
    float d;
    asm("v_max3_f32 %0, %1, %2, %3" : "=v"(d) : "v"(a), "v"(b), "v"(c));
    return d;
}

// ---- prep: reorder weights to [og][c][dy*10 + o2*5 + dx] (50/chunk) ----
__global__ void prep_weights_kernel(const float* __restrict__ w,
                                    float* __restrict__ ws) {
    int i = blockIdx.x * 256 + threadIdx.x;   // i over (o,c,dy,dx) row-major
    if (i < NW) {
        int dx = i % KK;  int q = i / KK;
        int dy = q % KK;  q /= KK;
        int c  = q % C_IN;
        int o  = q / C_IN;
        int og = o >> 1, o2 = o & 1;
        ws[(og * C_IN + c) * WCHUNK + dy * 10 + o2 * KK + dx] = w[i];
    }
}

template <bool USE_WS>
__global__ __launch_bounds__(512, 6)
void dil_kernel(const float* __restrict__ x,
                const float* __restrict__ wf,
                const float* __restrict__ ws,
                float* __restrict__ out) {
    __shared__ __align__(16) float xlds[CH][LROWS][LCOLS];      // 26,112 B

    const int tid = threadIdx.x;
    const int w0 = blockIdx.x * TW;
    const int h0 = blockIdx.y * TH;
    const int n  = blockIdx.z;
    const float* xn = x + (size_t)n * (C_IN * HH * WW);

    // wave -> (o-pair og, row-quad rq); lane -> 2-pixel column strip
    const int l   = tid & 63;
    const int og  = __builtin_amdgcn_readfirstlane((tid >> 6) & 3);
    const int rq  = __builtin_amdgcn_readfirstlane(tid >> 8);   // 0..1
    const int rbase = rq * 4;

    float acc[2][4][2];
    #pragma unroll
    for (int a = 0; a < 2; ++a)
        #pragma unroll
        for (int j = 0; j < 4; ++j) {
            acc[a][j][0] = -INFINITY;
            acc[a][j][1] = -INFINITY;
        }

    for (int h = 0; h < 2; ++h) {
        if (h) __syncthreads();        // all waves done with xlds half 0

        // ---- stage x half (4 channels), zero halo == reference zero pad ----
        for (int idx = tid; idx < XHALF; idx += 512) {
            int cc  = idx / (LROWS * (LCOLS / 2));
            int rem = idx - cc * (LROWS * (LCOLS / 2));
            int r   = rem / (LCOLS / 2);
            int jp  = rem - r * (LCOLS / 2);
            int gh = h0 - PADK + r;
            int gw = w0 - PADK + 2 * jp;
            float v0 = 0.f, v1 = 0.f;
            if ((unsigned)gh < (unsigned)HH) {
                const float* row = xn + ((size_t)(h * CH + cc) * HH + gh) * WW;
                if ((unsigned)gw < (unsigned)WW) v0 = row[gw];
                if ((unsigned)(gw + 1) < (unsigned)WW) v1 = row[gw + 1];
            }
            *(float2*)&xlds[cc][r][2 * jp] = make_float2(v0, v1);
        }
        __syncthreads();

        for (int ci = 0; ci < CH; ++ci) {
            // per-wave channel rotation within the half (max commutes):
            // staggers DS bursts across the 4 og-waves sharing each row set
            const int cl = (ci + og) & 3;      // local channel in this half
            const int c  = h * CH + cl;        // global channel

            // ---- weights -> SGPRs: 50 wave-uniform loads (s_load_dwordx16
            //      batches), reused across all 5 dy. ZERO DS instructions. ----
            float W[50];
            if (USE_WS) {
                const float* wb = ws + (og * C_IN + c) * WCHUNK;
                #pragma unroll
                for (int k = 0; k < 50; ++k) W[k] = wb[k];
            } else {
                #pragma unroll
                for (int o2 = 0; o2 < 2; ++o2)
                    #pragma unroll
                    for (int dy = 0; dy < KK; ++dy)
                        #pragma unroll
                        for (int dx = 0; dx < KK; ++dx)
                            W[dy * 10 + o2 * KK + dx] =
                                wf[(((og * 2 + o2) * C_IN + c) * KK + dy) * KK + dx];
            }

            // ---- x rows -> VGPRs: 24x ds_read_b64, only DS work per c ----
            float U[8][6];
            #pragma unroll
            for (int r = 0; r < 8; ++r) {
                const float* lr = &xlds[cl][rbase + r][2 * l];
                float2 a = *(const float2*)(lr);
                float2 b = *(const float2*)(lr + 2);
                float2 d = *(const float2*)(lr + 4);
                U[r][0] = a.x; U[r][1] = a.y;
                U[r][2] = b.x; U[r][3] = b.y;
                U[r][4] = d.x; U[r][5] = d.y;
            }

            // ---- 640 pure-VALU instrs; adds are v_add_f32 v,s,v ----
            #pragma unroll
            for (int dy = 0; dy < KK; ++dy) {
                #pragma unroll
                for (int j = 0; j < 4; ++j) {
                    const float u0 = U[dy + j][0], u1 = U[dy + j][1],
                                u2 = U[dy + j][2], u3 = U[dy + j][3],
                                u4 = U[dy + j][4], u5 = U[dy + j][5];
                    #pragma unroll
                    for (int o2 = 0; o2 < 2; ++o2) {
                        const int wb = dy * 10 + o2 * KK;
                        float t0 = u0 + W[wb + 0], t1 = u1 + W[wb + 1],
                              t2 = u2 + W[wb + 2], t3 = u3 + W[wb + 3],
                              t4 = u4 + W[wb + 4];
                        acc[o2][j][0] = max3f(acc[o2][j][0],
                                              max3f(t0, t1, t2),
                                              fmaxf(t3, t4));
                        float s0 = u1 + W[wb + 0], s1 = u2 + W[wb + 1],
                              s2 = u3 + W[wb + 2], s3 = u4 + W[wb + 3],
                              s4 = u5 + W[wb + 4];
                        acc[o2][j][1] = max3f(acc[o2][j][1],
                                              max3f(s0, s1, s2),
                                              fmaxf(s3, s4));
                    }
                }
            }
        }
    }

    // ---- store: 2 consecutive pixels -> one float2, coalesced ----
    float* onp = out + (size_t)n * (O_OUT * HH * WW);
    const int hB = h0 + rbase;
    const int wcol = w0 + 2 * l;
    #pragma unroll
    for (int o2 = 0; o2 < 2; ++o2) {
        const int o = og * 2 + o2;
        #pragma unroll
        for (int j = 0; j < 4; ++j) {
            float2 rr = make_float2(acc[o2][j][0], acc[o2][j][1]);
            *(float2*)(&onp[((size_t)o * HH + hB + j) * WW + wcol]) = rr;
        }
    }
}

extern "C" void kernel_launch(void* const* d_in, const int* in_sizes, int n_in,
                              void* d_out, int out_size, void* d_ws, size_t ws_size,
                              hipStream_t stream) {
    const float* x   = (const float*)d_in[0];
    const float* wgt = (const float*)d_in[1];
    float* out = (float*)d_out;

    dim3 grid(WW / TW, HH / TH, 4);   // (4, 64, 4) = 1024 blocks x 512 thr
    dim3 block(512);

    if (ws_size >= (size_t)(4 * C_IN * WCHUNK) * sizeof(float)) {
        float* ws = (float*)d_ws;
        prep_weights_kernel<<<(NW + 255) / 256, 256, 0, stream>>>(wgt, ws);
        dil_kernel<true><<<grid, block, 0, stream>>>(x, wgt, ws, out);
    } else {
        dil_kernel<false><<<grid, block, 0, stream>>>(x, wgt, nullptr, out);
    }
}